// Round 1
// baseline (527.321 us; speedup 1.0000x reference)
//
#include <hip/hip_runtime.h>
#include <stdint.h>

// Shapes fixed by the reference setup_inputs()
#define B 8
#define N 256
#define D 256
#define O 256
#define R 512
#define E 8192
#define F32_TINY 1.17549435e-38f

// ---------------- threefry2x32, key = (0, 42) --------------------------------
__device__ __forceinline__ void threefry2x32_k42(uint32_t x0, uint32_t x1,
                                                 uint32_t& o0, uint32_t& o1) {
  const uint32_t ks0 = 0u;
  const uint32_t ks1 = 42u;
  const uint32_t ks2 = 0u ^ 42u ^ 0x1BD11BDAu;
  x0 += ks0; x1 += ks1;
#define TF_R(r) { x0 += x1; x1 = (x1 << (r)) | (x1 >> (32 - (r))); x1 ^= x0; }
  TF_R(13) TF_R(15) TF_R(26) TF_R(6)
  x0 += ks1; x1 += ks2 + 1u;
  TF_R(17) TF_R(29) TF_R(16) TF_R(24)
  x0 += ks2; x1 += ks0 + 2u;
  TF_R(13) TF_R(15) TF_R(26) TF_R(6)
  x0 += ks0; x1 += ks1 + 3u;
  TF_R(17) TF_R(29) TF_R(16) TF_R(24)
  x0 += ks1; x1 += ks2 + 4u;
  TF_R(13) TF_R(15) TF_R(26) TF_R(6)
  x0 += ks2; x1 += ks0 + 5u;
#undef TF_R
  o0 = x0; o1 = x1;
}

// JAX uniform(minval=tiny, maxval=1) from 32 random bits, then gumbel.
__device__ __forceinline__ float gumbel_from_bits(uint32_t bits) {
  float f = __uint_as_float((bits >> 9) | 0x3f800000u) - 1.0f; // [0, 1-2^-23]
  float u = (f == 0.0f) ? F32_TINY : f;                        // f+tiny exact
  return -logf(-logf(u));
}

// ---------------- Wr = rel_features @ Wk + bk  [R,O] -------------------------
__global__ __launch_bounds__(256) void wr_kernel(const float* __restrict__ relf,
                                                 const float* __restrict__ Wk,
                                                 const float* __restrict__ bk,
                                                 float* __restrict__ Wr) {
  int r = blockIdx.x;      // [0,R)
  int o = threadIdx.x;     // [0,O)
  __shared__ float rrow[D];
  rrow[o] = relf[r * D + o];
  __syncthreads();
  double acc = 0.0;
  for (int d = 0; d < D; ++d)
    acc += (double)rrow[d] * (double)Wk[d * O + o];   // Wk reads coalesced in o
  Wr[r * O + o] = (float)acc + bk[o];
}

// ---------------- x2[b,n] = sum_d f2e^2  (sequential order == diag dot) -----
__global__ __launch_bounds__(256) void x2_kernel(const float* __restrict__ f2e,
                                                 float* __restrict__ x2) {
  int i = blockIdx.x * 256 + threadIdx.x;  // [0, B*N)
  const float* p = f2e + (size_t)i * D;
  double s = 0.0;
  for (int d = 0; d < D; ++d) s += (double)p[d] * (double)p[d];
  x2[i] = (float)s;
}

// ---------------- sim + logits rows ------------------------------------------
// One block per (b,n); thread m computes dot(f2e[b,n], f2e[b,m]) then the
// f32 elementwise chain exactly as XLA: d2 = (x2n + x2m) - 2*dot;
// t = sqrt(max(d2,0)); softmax over -t; logits = log(sim).
__global__ __launch_bounds__(256) void sim_kernel(const float* __restrict__ f2e,
                                                  const float* __restrict__ x2,
                                                  float* __restrict__ sim,
                                                  float* __restrict__ logits) {
  int bn = blockIdx.x;          // b*N + n
  int b = bn >> 8;
  int m = threadIdx.x;
  __shared__ float arow[D];
  __shared__ float red[N];
  __shared__ double sd[N];
  arow[m] = f2e[(size_t)bn * D + m];
  __syncthreads();
  const float* brow = f2e + (size_t)(b * N + m) * D;
  double acc = 0.0;
  for (int d = 0; d < D; ++d) acc += (double)arow[d] * (double)brow[d];
  float dotf = (float)acc;
  float d2 = (x2[bn] + x2[b * N + m]) - 2.0f * dotf;  // ==0 exactly at m==n
  float t = sqrtf(fmaxf(d2, 0.0f));
  float neg = -t;
  // row max of neg (exact, order-independent)
  red[m] = neg;
  __syncthreads();
  for (int off = 128; off > 0; off >>= 1) {
    if (m < off) red[m] = fmaxf(red[m], red[m + off]);
    __syncthreads();
  }
  float rowmax = red[0];
  __syncthreads();
  float p = expf(neg - rowmax);
  sd[m] = (double)p;
  __syncthreads();
  for (int off = 128; off > 0; off >>= 1) {
    if (m < off) sd[m] += sd[m + off];
    __syncthreads();
  }
  float denom = (float)sd[0];
  float sv = p / denom;
  sim[(size_t)bn * N + m] = sv;
  logits[(size_t)bn * N + m] = logf(sv);
}

// ---------------- cand[b,n,m] = (prob > eps) & (edge_mat < 1) ----------------
__global__ __launch_bounds__(256) void cand_kernel(const float* __restrict__ sim,
                                                   const float* __restrict__ score,
                                                   const int* __restrict__ edge,
                                                   const int* __restrict__ epsp,
                                                   unsigned char* __restrict__ cand) {
  int bn = blockIdx.x;
  int b = bn >> 8;
  int m = threadIdx.x;
  __shared__ float srow[N];
  srow[m] = sim[(size_t)bn * N + m];
  __syncthreads();
  const float* sc = score + (size_t)(b * N + m) * N;  // score_mat[b,m,:]
  double acc = 0.0;
  for (int k = 0; k < N; ++k) acc += (double)srow[k] * (double)sc[k];
  float prob = (float)acc;
  float epsv = (float)epsp[0];
  int em = edge[(size_t)bn * N + m];
  cand[(size_t)bn * N + m] = (prob > epsv && em < 1) ? 1 : 0;
}

// ---------------- gumbel-max sampling + counts scatter -----------------------
// One wave per (b,n,c) row; lane handles 4 of the 256 categories.
// bits[i] = o0^o1, (o0,o1)=threefry(key,(0,i)), i = ((b*N+n)*N+c)*N + k.
__global__ __launch_bounds__(256) void sample_kernel(const float* __restrict__ logits,
                                                     const unsigned char* __restrict__ cand,
                                                     const int* __restrict__ edge,
                                                     float* __restrict__ counts) {
  int wid = threadIdx.x >> 6;
  int lane = threadIdx.x & 63;
  int row = blockIdx.x * 4 + wid;          // [0, B*N*N)
  int b = row >> 16;
  int n = (row >> 8) & 255;
  int c = row & 255;
  const float* lrow = logits + (size_t)(b * N + n) * N;
  uint32_t base = (uint32_t)row << 8;      // row*N, fits (B*N^3 < 2^28)
  float bestv = -1e30f;
  int besti = 0;
  for (int q = 0; q < 4; ++q) {
    int k = q * 64 + lane;                 // coalesced logits reads
    uint32_t o0, o1;
    threefry2x32_k42(0u, base + (uint32_t)k, o0, o1);
    float g = gumbel_from_bits(o0 ^ o1);
    float v = g + lrow[k];                 // gumbel + logits (f32, JAX order)
    if (v > bestv || (v == bestv && k < besti)) { bestv = v; besti = k; }
  }
  // wave argmax, first-index tie-break (assoc+comm comparator)
  for (int off = 32; off > 0; off >>= 1) {
    float ov = __shfl_down(bestv, off);
    int oi = __shfl_down(besti, off);
    if (ov > bestv || (ov == bestv && oi < besti)) { bestv = ov; besti = oi; }
  }
  if (lane == 0) {
    if (cand[row]) {
      int nr = edge[(size_t)(b * N + besti) * N + c];
      if (nr != 0) {
        atomicAdd(&counts[(size_t)(b * N + n) * R + nr], 1.0f);
        atomicAdd(&counts[(size_t)(b * N + c) * R + nr], 1.0f);
      }
    }
  }
}

// ---------------- batch head/tail incidence ----------------------------------
__global__ __launch_bounds__(256) void batch_kernel(const int* __restrict__ heads,
                                                    const int* __restrict__ rels,
                                                    const int* __restrict__ tails,
                                                    float* __restrict__ counts) {
  int i = blockIdx.x * 256 + threadIdx.x;  // [0, B*E)
  int b = i >> 13;                         // E = 8192
  int h = heads[i], r = rels[i], t = tails[i];
  atomicAdd(&counts[(size_t)(b * N + h) * R + r], 1.0f);
  atomicAdd(&counts[(size_t)(b * N + t) * R + r], 1.0f);
}

// ---------------- out = relu(counts @ Wr) ------------------------------------
__global__ __launch_bounds__(256) void out_kernel(const float* __restrict__ counts,
                                                  const float* __restrict__ Wr,
                                                  float* __restrict__ out) {
  int bn = blockIdx.x;
  int o = threadIdx.x;
  __shared__ float crow[R];
  crow[o] = counts[(size_t)bn * R + o];
  crow[o + 256] = counts[(size_t)bn * R + 256 + o];
  __syncthreads();
  double acc = 0.0;
  for (int r = 0; r < R; ++r)
    acc += (double)crow[r] * (double)Wr[r * O + o];   // Wr coalesced in o
  out[(size_t)bn * O + o] = fmaxf((float)acc, 0.0f);
}

extern "C" void kernel_launch(void* const* d_in, const int* in_sizes, int n_in,
                              void* d_out, int out_size, void* d_ws, size_t ws_size,
                              hipStream_t stream) {
  (void)in_sizes; (void)n_in; (void)out_size; (void)ws_size;
  const float* f2e   = (const float*)d_in[0];
  const float* score = (const float*)d_in[1];
  const float* relf  = (const float*)d_in[2];
  const float* Wk    = (const float*)d_in[3];
  const float* bk    = (const float*)d_in[4];
  // d_in[5] local_entity: unused by the reference computation
  const int* heads   = (const int*)d_in[6];
  const int* rels    = (const int*)d_in[7];
  const int* tails   = (const int*)d_in[8];
  const int* edge    = (const int*)d_in[9];
  const int* epsp    = (const int*)d_in[10];
  float* out = (float*)d_out;

  // workspace layout (floats): sim | logits | x2 | Wr | counts | cand(bytes)
  float* ws     = (float*)d_ws;
  float* sim    = ws;
  float* logits = sim + (size_t)B * N * N;       // 524288
  float* x2     = logits + (size_t)B * N * N;    // 524288
  float* Wr     = x2 + (size_t)B * N;            // 2048
  float* counts = Wr + (size_t)R * O;            // 131072
  unsigned char* cand = (unsigned char*)(counts + (size_t)B * N * R);

  hipMemsetAsync(counts, 0, (size_t)B * N * R * sizeof(float), stream);

  wr_kernel<<<R, 256, 0, stream>>>(relf, Wk, bk, Wr);
  x2_kernel<<<(B * N) / 256, 256, 0, stream>>>(f2e, x2);
  sim_kernel<<<B * N, 256, 0, stream>>>(f2e, x2, sim, logits);
  cand_kernel<<<B * N, 256, 0, stream>>>(sim, score, edge, epsp, cand);
  sample_kernel<<<(B * N * N) / 4, 256, 0, stream>>>(logits, cand, edge, counts);
  batch_kernel<<<(B * E) / 256, 256, 0, stream>>>(heads, rels, tails, counts);
  out_kernel<<<B * N, 256, 0, stream>>>(counts, Wr, out);
}

// Round 2
// 282.480 us; speedup vs baseline: 1.8668x; 1.8668x over previous
//
#include <hip/hip_runtime.h>
#include <stdint.h>

// Shapes fixed by the reference setup_inputs()
#define B 8
#define N 256
#define D 256
#define O 256
#define R 512
#define E 8192
#define F32_TINY 1.17549435e-38f

// ---------------- threefry2x32, key = (0, 42) --------------------------------
__device__ __forceinline__ void threefry2x32_k42(uint32_t x0, uint32_t x1,
                                                 uint32_t& o0, uint32_t& o1) {
  const uint32_t ks0 = 0u;
  const uint32_t ks1 = 42u;
  const uint32_t ks2 = 0u ^ 42u ^ 0x1BD11BDAu;
  x0 += ks0; x1 += ks1;
#define TF_R(r) { x0 += x1; x1 = (x1 << (r)) | (x1 >> (32 - (r))); x1 ^= x0; }
  TF_R(13) TF_R(15) TF_R(26) TF_R(6)
  x0 += ks1; x1 += ks2 + 1u;
  TF_R(17) TF_R(29) TF_R(16) TF_R(24)
  x0 += ks2; x1 += ks0 + 2u;
  TF_R(13) TF_R(15) TF_R(26) TF_R(6)
  x0 += ks0; x1 += ks1 + 3u;
  TF_R(17) TF_R(29) TF_R(16) TF_R(24)
  x0 += ks1; x1 += ks2 + 4u;
  TF_R(13) TF_R(15) TF_R(26) TF_R(6)
  x0 += ks2; x1 += ks0 + 5u;
#undef TF_R
  o0 = x0; o1 = x1;
}

// JAX uniform(minval=tiny, maxval=1) from 32 random bits, then gumbel.
__device__ __forceinline__ float gumbel_from_bits_f(float f) {
  float u = (f == 0.0f) ? F32_TINY : f;
  return -logf(-logf(u));
}

// ---------------- Wr = rel_features @ Wk + bk  [R,O] -------------------------
__global__ __launch_bounds__(256) void wr_kernel(const float* __restrict__ relf,
                                                 const float* __restrict__ Wk,
                                                 const float* __restrict__ bk,
                                                 float* __restrict__ Wr) {
  int r = blockIdx.x;      // [0,R)
  int o = threadIdx.x;     // [0,O)
  __shared__ float rrow[D];
  rrow[o] = relf[r * D + o];
  __syncthreads();
  double acc = 0.0;
  for (int d = 0; d < D; ++d)
    acc += (double)rrow[d] * (double)Wk[d * O + o];   // Wk reads coalesced in o
  Wr[r * O + o] = (float)acc + bk[o];
}

// ---------------- x2[b,n] = sum_d f2e^2 --------------------------------------
__global__ __launch_bounds__(256) void x2_kernel(const float* __restrict__ f2e,
                                                 float* __restrict__ x2) {
  int i = blockIdx.x * 256 + threadIdx.x;  // [0, B*N)
  const float* p = f2e + (size_t)i * D;
  double s = 0.0;
  for (int d = 0; d < D; ++d) s += (double)p[d] * (double)p[d];
  x2[i] = (float)s;
}

// ---------------- sim + logits rows + per-row {l_n, Lmax} --------------------
__global__ __launch_bounds__(256) void sim_kernel(const float* __restrict__ f2e,
                                                  const float* __restrict__ x2,
                                                  float* __restrict__ sim,
                                                  float* __restrict__ logits,
                                                  float* __restrict__ laux) {
  int bn = blockIdx.x;          // b*N + n
  int b = bn >> 8;
  int diag = bn & 255;
  int m = threadIdx.x;
  __shared__ float arow[D];
  __shared__ float red[N];
  __shared__ double sd[N];
  __shared__ float ldiag_sh;
  arow[m] = f2e[(size_t)bn * D + m];
  __syncthreads();
  const float* brow = f2e + (size_t)(b * N + m) * D;
  double acc = 0.0;
  for (int d = 0; d < D; ++d) acc += (double)arow[d] * (double)brow[d];
  float dotf = (float)acc;
  float d2 = (x2[bn] + x2[b * N + m]) - 2.0f * dotf;  // ==0 exactly at m==diag
  float t = sqrtf(fmaxf(d2, 0.0f));
  float neg = -t;
  red[m] = neg;
  __syncthreads();
  for (int off = 128; off > 0; off >>= 1) {
    if (m < off) red[m] = fmaxf(red[m], red[m + off]);
    __syncthreads();
  }
  float rowmax = red[0];
  __syncthreads();
  float p = expf(neg - rowmax);
  sd[m] = (double)p;
  __syncthreads();
  for (int off = 128; off > 0; off >>= 1) {
    if (m < off) sd[m] += sd[m + off];
    __syncthreads();
  }
  float denom = (float)sd[0];
  float sv = p / denom;
  float lv = logf(sv);
  sim[(size_t)bn * N + m] = sv;
  logits[(size_t)bn * N + m] = lv;
  // reduce {l_n, Lmax=max off-diag logit}
  if (m == diag) ldiag_sh = lv;
  red[m] = (m == diag) ? -3.4e38f : lv;
  __syncthreads();
  for (int off = 128; off > 0; off >>= 1) {
    if (m < off) red[m] = fmaxf(red[m], red[m + off]);
    __syncthreads();
  }
  if (m == 0) {
    laux[2 * bn + 0] = ldiag_sh;
    laux[2 * bn + 1] = red[0];
  }
}

// ---------------- cand[b,n,m] = (prob > eps) & (edge_mat < 1) ----------------
__global__ __launch_bounds__(256) void cand_kernel(const float* __restrict__ sim,
                                                   const float* __restrict__ score,
                                                   const int* __restrict__ edge,
                                                   const int* __restrict__ epsp,
                                                   unsigned char* __restrict__ cand) {
  int bn = blockIdx.x;
  int b = bn >> 8;
  int m = threadIdx.x;
  __shared__ float srow[N];
  srow[m] = sim[(size_t)bn * N + m];
  __syncthreads();
  const float* sc = score + (size_t)(b * N + m) * N;  // score_mat[b,m,:]
  double acc = 0.0;
  for (int k = 0; k < N; ++k) acc += (double)srow[k] * (double)sc[k];
  float prob = (float)acc;
  float epsv = (float)epsp[0];
  int em = edge[(size_t)bn * N + m];
  cand[(size_t)bn * N + m] = (prob > epsv && em < 1) ? 1 : 0;
}

// ---------------- gumbel-max sampling + counts scatter -----------------------
// One wave per (b,n,c) row. Fast path: compute uniforms only and screen
// against a conservative threshold derived from v_n = g_n + l_n. Only if some
// element could beat v_n does the wave run the exact full argmax (rare).
__global__ __launch_bounds__(256) void sample_kernel(const float* __restrict__ logits,
                                                     const float* __restrict__ laux,
                                                     const unsigned char* __restrict__ cand,
                                                     const int* __restrict__ edge,
                                                     float* __restrict__ counts) {
  int wid = threadIdx.x >> 6;
  int lane = threadIdx.x & 63;
  int row = blockIdx.x * 4 + wid;          // [0, B*N*N)
  if (!cand[row]) return;                  // wave-uniform: no contribution possible
  int b = row >> 16;
  int n = (row >> 8) & 255;
  int c = row & 255;
  uint32_t base = (uint32_t)row << 8;      // row*N
  float u0, u1, u2, u3;
  {
    uint32_t a0, a1;
#define GEN_U(q, dst)                                                     \
    threefry2x32_k42(0u, base + (uint32_t)((q) * 64 + lane), a0, a1);      \
    dst = __uint_as_float((((a0 ^ a1) >> 9)) | 0x3f800000u) - 1.0f;
    GEN_U(0, u0) GEN_U(1, u1) GEN_U(2, u2) GEN_U(3, u3)
#undef GEN_U
  }
  // exact v_n (diag element), broadcast from its owner lane
  float l_n  = laux[2 * ((b << 8) + n) + 0];
  float Lmax = laux[2 * ((b << 8) + n) + 1];
  int qo = n >> 6;
  float uo = (qo == 0) ? u0 : (qo == 1) ? u1 : (qo == 2) ? u2 : u3;
  float u_n = __shfl(uo, n & 63);
  float v_n = gumbel_from_bits_f(u_n) + l_n;
  // conservative screen: u <= u_thr  =>  g + l_k <= v_n - 0.125 + eps < v_n
  float thr_g = (v_n - Lmax) - 0.125f;
  float u_thr = expf(-expf(-thr_g));
  bool owner = (lane == (n & 63));
  bool anyc = ((u0 > u_thr) && !(owner && qo == 0)) |
              ((u1 > u_thr) && !(owner && qo == 1)) |
              ((u2 > u_thr) && !(owner && qo == 2)) |
              ((u3 > u_thr) && !(owner && qo == 3));
  if (!__any(anyc)) return;                // argmax = n -> new_rel = 0 -> nothing

  // ---- slow path (expected ~2 rows per entire launch): exact full argmax ----
  const float* lrow = logits + (size_t)((b << 8) + n) * N;
  float bestv = -1e30f;
  int besti = 0;
  for (int q = 0; q < 4; ++q) {
    int k = q * 64 + lane;
    uint32_t o0, o1;
    threefry2x32_k42(0u, base + (uint32_t)k, o0, o1);
    uint32_t bits = o0 ^ o1;
    float f = __uint_as_float((bits >> 9) | 0x3f800000u) - 1.0f;
    float g = gumbel_from_bits_f(f);
    float v = g + lrow[k];
    if (v > bestv || (v == bestv && k < besti)) { bestv = v; besti = k; }
  }
  for (int off = 32; off > 0; off >>= 1) {
    float ov = __shfl_down(bestv, off);
    int oi = __shfl_down(besti, off);
    if (ov > bestv || (ov == bestv && oi < besti)) { bestv = ov; besti = oi; }
  }
  if (lane == 0) {
    int nr = edge[(size_t)((b << 8) + besti) * N + c];
    if (nr != 0) {
      atomicAdd(&counts[(size_t)((b << 8) + n) * R + nr], 1.0f);
      atomicAdd(&counts[(size_t)((b << 8) + c) * R + nr], 1.0f);
    }
  }
}

// ---------------- batch head/tail incidence ----------------------------------
__global__ __launch_bounds__(256) void batch_kernel(const int* __restrict__ heads,
                                                    const int* __restrict__ rels,
                                                    const int* __restrict__ tails,
                                                    float* __restrict__ counts) {
  int i = blockIdx.x * 256 + threadIdx.x;  // [0, B*E)
  int b = i >> 13;                         // E = 8192
  int h = heads[i], r = rels[i], t = tails[i];
  atomicAdd(&counts[(size_t)(b * N + h) * R + r], 1.0f);
  atomicAdd(&counts[(size_t)(b * N + t) * R + r], 1.0f);
}

// ---------------- out = relu(counts @ Wr) ------------------------------------
__global__ __launch_bounds__(256) void out_kernel(const float* __restrict__ counts,
                                                  const float* __restrict__ Wr,
                                                  float* __restrict__ out) {
  int bn = blockIdx.x;
  int o = threadIdx.x;
  __shared__ float crow[R];
  crow[o] = counts[(size_t)bn * R + o];
  crow[o + 256] = counts[(size_t)bn * R + 256 + o];
  __syncthreads();
  double acc = 0.0;
  for (int r = 0; r < R; ++r)
    acc += (double)crow[r] * (double)Wr[r * O + o];   // Wr coalesced in o
  out[(size_t)bn * O + o] = fmaxf((float)acc, 0.0f);
}

extern "C" void kernel_launch(void* const* d_in, const int* in_sizes, int n_in,
                              void* d_out, int out_size, void* d_ws, size_t ws_size,
                              hipStream_t stream) {
  (void)in_sizes; (void)n_in; (void)out_size; (void)ws_size;
  const float* f2e   = (const float*)d_in[0];
  const float* score = (const float*)d_in[1];
  const float* relf  = (const float*)d_in[2];
  const float* Wk    = (const float*)d_in[3];
  const float* bk    = (const float*)d_in[4];
  // d_in[5] local_entity: unused by the reference computation
  const int* heads   = (const int*)d_in[6];
  const int* rels    = (const int*)d_in[7];
  const int* tails   = (const int*)d_in[8];
  const int* edge    = (const int*)d_in[9];
  const int* epsp    = (const int*)d_in[10];
  float* out = (float*)d_out;

  // workspace layout (floats): sim | logits | x2 | Wr | counts | cand | laux
  float* ws     = (float*)d_ws;
  float* sim    = ws;
  float* logits = sim + (size_t)B * N * N;       // 524288
  float* x2     = logits + (size_t)B * N * N;    // 524288
  float* Wr     = x2 + (size_t)B * N;            // 2048
  float* counts = Wr + (size_t)R * O;            // 131072
  unsigned char* cand = (unsigned char*)(counts + (size_t)B * N * R);
  float* laux   = (float*)(cand + (size_t)B * N * N);  // [B*N][2]

  hipMemsetAsync(counts, 0, (size_t)B * N * R * sizeof(float), stream);

  wr_kernel<<<R, 256, 0, stream>>>(relf, Wk, bk, Wr);
  x2_kernel<<<(B * N) / 256, 256, 0, stream>>>(f2e, x2);
  sim_kernel<<<B * N, 256, 0, stream>>>(f2e, x2, sim, logits, laux);
  cand_kernel<<<B * N, 256, 0, stream>>>(sim, score, edge, epsp, cand);
  sample_kernel<<<(B * N * N) / 4, 256, 0, stream>>>(logits, laux, cand, edge, counts);
  batch_kernel<<<(B * E) / 256, 256, 0, stream>>>(heads, rels, tails, counts);
  out_kernel<<<B * N, 256, 0, stream>>>(counts, Wr, out);
}

// Round 3
// 171.627 us; speedup vs baseline: 3.0725x; 1.6459x over previous
//
#include <hip/hip_runtime.h>
#include <stdint.h>

// Shapes fixed by the reference setup_inputs()
#define B 8
#define N 256
#define D 256
#define O 256
#define R 512
#define E 8192
#define TR 4
#define F32_TINY 1.17549435e-38f

// ---------------- threefry2x32, key = (0, 42) --------------------------------
__device__ __forceinline__ void threefry2x32_k42(uint32_t x0, uint32_t x1,
                                                 uint32_t& o0, uint32_t& o1) {
  const uint32_t ks0 = 0u;
  const uint32_t ks1 = 42u;
  const uint32_t ks2 = 0u ^ 42u ^ 0x1BD11BDAu;
  x0 += ks0; x1 += ks1;
#define TF_R(r) { x0 += x1; x1 = (x1 << (r)) | (x1 >> (32 - (r))); x1 ^= x0; }
  TF_R(13) TF_R(15) TF_R(26) TF_R(6)
  x0 += ks1; x1 += ks2 + 1u;
  TF_R(17) TF_R(29) TF_R(16) TF_R(24)
  x0 += ks2; x1 += ks0 + 2u;
  TF_R(13) TF_R(15) TF_R(26) TF_R(6)
  x0 += ks0; x1 += ks1 + 3u;
  TF_R(17) TF_R(29) TF_R(16) TF_R(24)
  x0 += ks1; x1 += ks2 + 4u;
  TF_R(13) TF_R(15) TF_R(26) TF_R(6)
  x0 += ks2; x1 += ks0 + 5u;
#undef TF_R
  o0 = x0; o1 = x1;
}

__device__ __forceinline__ float gumbel_from_bits_f(float f) {
  float u = (f == 0.0f) ? F32_TINY : f;
  return -logf(-logf(u));
}

// ---------------- batched 256x256 transpose (score and f2e) ------------------
__global__ __launch_bounds__(256) void transpose_kernel(const float* __restrict__ score,
                                                        float* __restrict__ scoreT,
                                                        const float* __restrict__ f2e,
                                                        float* __restrict__ f2eT) {
  __shared__ float tile[64][65];
  int blk = blockIdx.x;               // 256 blocks: 128 per tensor
  const float* src = (blk < 128) ? score : f2e;
  float* dst = (blk < 128) ? scoreT : f2eT;
  int b7 = blk & 127;
  int bb = b7 >> 4, t = b7 & 15, ti = t >> 2, tj = t & 3;
  size_t base = (size_t)bb * 65536;
  int c = threadIdx.x & 63, r4 = threadIdx.x >> 6;
#pragma unroll
  for (int rr = 0; rr < 64; rr += 4) {
    int row = rr + r4;
    tile[row][c] = src[base + (size_t)(ti * 64 + row) * 256 + tj * 64 + c];
  }
  __syncthreads();
#pragma unroll
  for (int rr = 0; rr < 64; rr += 4) {
    int row = rr + r4;
    dst[base + (size_t)(tj * 64 + row) * 256 + ti * 64 + c] = tile[c][row];
  }
}

// ---------------- x2[b,n] = sum_d f2e^2  (ascending d, f64) ------------------
__global__ __launch_bounds__(256) void x2_kernel(const float* __restrict__ f2e,
                                                 float* __restrict__ x2) {
  int i = blockIdx.x * 256 + threadIdx.x;  // [0, B*N)
  const float4* p = (const float4*)(f2e + (size_t)i * D);
  double s = 0.0;
  for (int d = 0; d < D / 4; ++d) {
    float4 v = p[d];
    s += (double)v.x * v.x; s += (double)v.y * v.y;
    s += (double)v.z * v.z; s += (double)v.w * v.w;
  }
  x2[i] = (float)s;
}

// ---------------- Wr = rel_features @ Wk + bk  [R,O], 4 rows/block -----------
__global__ __launch_bounds__(256) void wr_kernel(const float* __restrict__ relf,
                                                 const float* __restrict__ Wk,
                                                 const float* __restrict__ bk,
                                                 float* __restrict__ Wr) {
  int r0 = blockIdx.x * TR;
  int o = threadIdx.x;
  __shared__ float rrow[TR][D];
#pragma unroll
  for (int r = 0; r < TR; ++r) rrow[r][o] = relf[(size_t)(r0 + r) * D + o];
  __syncthreads();
  double acc[TR] = {0, 0, 0, 0};
  for (int d = 0; d < D; d += 4) {
    float w0 = Wk[(size_t)(d + 0) * O + o];
    float w1 = Wk[(size_t)(d + 1) * O + o];
    float w2 = Wk[(size_t)(d + 2) * O + o];
    float w3 = Wk[(size_t)(d + 3) * O + o];
#pragma unroll
    for (int r = 0; r < TR; ++r) {
      float4 a = *(const float4*)&rrow[r][d];
      acc[r] += (double)a.x * w0; acc[r] += (double)a.y * w1;
      acc[r] += (double)a.z * w2; acc[r] += (double)a.w * w3;
    }
  }
  float bv = bk[o];
#pragma unroll
  for (int r = 0; r < TR; ++r) Wr[(size_t)(r0 + r) * O + o] = (float)acc[r] + bv;
}

// ---------------- sim + logits, 4 rows/block, softmax per wave ---------------
__global__ __launch_bounds__(256) void sim_kernel(const float* __restrict__ f2e,
                                                  const float* __restrict__ f2eT,
                                                  const float* __restrict__ x2,
                                                  float* __restrict__ sim,
                                                  float* __restrict__ logits,
                                                  float* __restrict__ laux) {
  int bn0 = blockIdx.x * TR;    // 4 consecutive (b,n) rows, same b
  int b = bn0 >> 8;
  int tid = threadIdx.x, lane = tid & 63, w = tid >> 6;
  __shared__ float arow[TR][256];
  __shared__ float nbuf[TR][256];
#pragma unroll
  for (int r = 0; r < TR; ++r) arow[r][tid] = f2e[(size_t)(bn0 + r) * 256 + tid];
  __syncthreads();
  double acc[TR] = {0, 0, 0, 0};
  const float* fT = f2eT + (size_t)b * 65536 + tid;
  for (int dd = 0; dd < 256; dd += 4) {
    float b0 = fT[(size_t)(dd + 0) * 256];
    float b1 = fT[(size_t)(dd + 1) * 256];
    float b2 = fT[(size_t)(dd + 2) * 256];
    float b3 = fT[(size_t)(dd + 3) * 256];
#pragma unroll
    for (int r = 0; r < TR; ++r) {
      float4 a = *(const float4*)&arow[r][dd];
      acc[r] += (double)a.x * b0; acc[r] += (double)a.y * b1;   // ascending d:
      acc[r] += (double)a.z * b2; acc[r] += (double)a.w * b3;   // matches x2
    }
  }
  float x2c = x2[b * 256 + tid];
#pragma unroll
  for (int r = 0; r < TR; ++r) {
    float d2 = (x2[bn0 + r] + x2c) - 2.0f * (float)acc[r];  // ==0 exactly at diag
    nbuf[r][tid] = -sqrtf(fmaxf(d2, 0.0f));
  }
  __syncthreads();
  // wave w owns row bn0+w: softmax + logits + laux
  float v0 = nbuf[w][lane], v1 = nbuf[w][lane + 64],
        v2 = nbuf[w][lane + 128], v3 = nbuf[w][lane + 192];
  float mx = fmaxf(fmaxf(v0, v1), fmaxf(v2, v3));
#pragma unroll
  for (int off = 32; off > 0; off >>= 1) mx = fmaxf(mx, __shfl_xor(mx, off));
  float p0 = expf(v0 - mx), p1 = expf(v1 - mx), p2 = expf(v2 - mx), p3 = expf(v3 - mx);
  double sd = (double)p0 + (double)p1 + (double)p2 + (double)p3;
#pragma unroll
  for (int off = 32; off > 0; off >>= 1) sd += __shfl_xor(sd, off);
  float denom = (float)sd;
  float s0 = p0 / denom, s1 = p1 / denom, s2 = p2 / denom, s3 = p3 / denom;
  size_t rb = (size_t)(bn0 + w) * 256;
  sim[rb + lane] = s0; sim[rb + lane + 64] = s1;
  sim[rb + lane + 128] = s2; sim[rb + lane + 192] = s3;
  float l0 = logf(s0), l1 = logf(s1), l2 = logf(s2), l3 = logf(s3);
  logits[rb + lane] = l0; logits[rb + lane + 64] = l1;
  logits[rb + lane + 128] = l2; logits[rb + lane + 192] = l3;
  int dm = (bn0 + w) & 255;
  int dj = dm >> 6, dl = dm & 63;
  float e0 = (dj == 0 && lane == dl) ? -3.4e38f : l0;
  float e1 = (dj == 1 && lane == dl) ? -3.4e38f : l1;
  float e2 = (dj == 2 && lane == dl) ? -3.4e38f : l2;
  float e3 = (dj == 3 && lane == dl) ? -3.4e38f : l3;
  float Lm = fmaxf(fmaxf(e0, e1), fmaxf(e2, e3));
#pragma unroll
  for (int off = 32; off > 0; off >>= 1) Lm = fmaxf(Lm, __shfl_xor(Lm, off));
  float lown = (dj == 0) ? l0 : (dj == 1) ? l1 : (dj == 2) ? l2 : l3;
  float l_n = __shfl(lown, dl);
  if (lane == 0) {
    laux[2 * (bn0 + w) + 0] = l_n;
    laux[2 * (bn0 + w) + 1] = Lm;
  }
}

// ---------------- cand = (sim @ score^T > eps) & (edge < 1), 4 rows/block ----
__global__ __launch_bounds__(256) void cand_kernel(const float* __restrict__ sim,
                                                   const float* __restrict__ scoreT,
                                                   const int* __restrict__ edge,
                                                   const int* __restrict__ epsp,
                                                   unsigned char* __restrict__ cand) {
  int bn0 = blockIdx.x * TR;
  int b = bn0 >> 8;
  int tid = threadIdx.x;
  __shared__ float srow[TR][256];
#pragma unroll
  for (int r = 0; r < TR; ++r) srow[r][tid] = sim[(size_t)(bn0 + r) * 256 + tid];
  __syncthreads();
  double acc[TR] = {0, 0, 0, 0};
  const float* sT = scoreT + (size_t)b * 65536 + tid;
  for (int kk = 0; kk < 256; kk += 4) {
    float b0 = sT[(size_t)(kk + 0) * 256];
    float b1 = sT[(size_t)(kk + 1) * 256];
    float b2 = sT[(size_t)(kk + 2) * 256];
    float b3 = sT[(size_t)(kk + 3) * 256];
#pragma unroll
    for (int r = 0; r < TR; ++r) {
      float4 a = *(const float4*)&srow[r][kk];
      acc[r] += (double)a.x * b0; acc[r] += (double)a.y * b1;
      acc[r] += (double)a.z * b2; acc[r] += (double)a.w * b3;
    }
  }
  float epsv = (float)epsp[0];
#pragma unroll
  for (int r = 0; r < TR; ++r) {
    int em = edge[(size_t)(bn0 + r) * 256 + tid];
    cand[(size_t)(bn0 + r) * 256 + tid] =
        ((float)acc[r] > epsv && em < 1) ? 1 : 0;
  }
}

// ---------------- gumbel-max sampling + counts scatter -----------------------
__global__ __launch_bounds__(256) void sample_kernel(const float* __restrict__ logits,
                                                     const float* __restrict__ laux,
                                                     const unsigned char* __restrict__ cand,
                                                     const int* __restrict__ edge,
                                                     float* __restrict__ counts) {
  int wid = threadIdx.x >> 6;
  int lane = threadIdx.x & 63;
  int row = blockIdx.x * 4 + wid;          // [0, B*N*N)
  if (!cand[row]) return;                  // wave-uniform: no contribution possible
  int b = row >> 16;
  int n = (row >> 8) & 255;
  int c = row & 255;
  uint32_t base = (uint32_t)row << 8;      // row*N
  float u0, u1, u2, u3;
  {
    uint32_t a0, a1;
#define GEN_U(q, dst)                                                     \
    threefry2x32_k42(0u, base + (uint32_t)((q) * 64 + lane), a0, a1);      \
    dst = __uint_as_float((((a0 ^ a1) >> 9)) | 0x3f800000u) - 1.0f;
    GEN_U(0, u0) GEN_U(1, u1) GEN_U(2, u2) GEN_U(3, u3)
#undef GEN_U
  }
  float l_n  = laux[2 * ((b << 8) + n) + 0];
  float Lmax = laux[2 * ((b << 8) + n) + 1];
  int qo = n >> 6;
  float uo = (qo == 0) ? u0 : (qo == 1) ? u1 : (qo == 2) ? u2 : u3;
  float u_n = __shfl(uo, n & 63);
  float v_n = gumbel_from_bits_f(u_n) + l_n;
  float thr_g = (v_n - Lmax) - 0.125f;
  float u_thr = expf(-expf(-thr_g));
  bool owner = (lane == (n & 63));
  bool anyc = ((u0 > u_thr) && !(owner && qo == 0)) |
              ((u1 > u_thr) && !(owner && qo == 1)) |
              ((u2 > u_thr) && !(owner && qo == 2)) |
              ((u3 > u_thr) && !(owner && qo == 3));
  if (!__any(anyc)) return;                // argmax = n -> new_rel = 0 -> nothing

  // ---- slow path (rare): exact full argmax ----
  const float* lrow = logits + (size_t)((b << 8) + n) * N;
  float bestv = -1e30f;
  int besti = 0;
  for (int q = 0; q < 4; ++q) {
    int k = q * 64 + lane;
    uint32_t o0, o1;
    threefry2x32_k42(0u, base + (uint32_t)k, o0, o1);
    uint32_t bits = o0 ^ o1;
    float f = __uint_as_float((bits >> 9) | 0x3f800000u) - 1.0f;
    float g = gumbel_from_bits_f(f);
    float v = g + lrow[k];
    if (v > bestv || (v == bestv && k < besti)) { bestv = v; besti = k; }
  }
  for (int off = 32; off > 0; off >>= 1) {
    float ov = __shfl_down(bestv, off);
    int oi = __shfl_down(besti, off);
    if (ov > bestv || (ov == bestv && oi < besti)) { bestv = ov; besti = oi; }
  }
  if (lane == 0) {
    int nr = edge[(size_t)((b << 8) + besti) * N + c];
    if (nr != 0) {
      atomicAdd(&counts[(size_t)((b << 8) + n) * R + nr], 1.0f);
      atomicAdd(&counts[(size_t)((b << 8) + c) * R + nr], 1.0f);
    }
  }
}

// ---------------- batch head/tail incidence ----------------------------------
__global__ __launch_bounds__(256) void batch_kernel(const int* __restrict__ heads,
                                                    const int* __restrict__ rels,
                                                    const int* __restrict__ tails,
                                                    float* __restrict__ counts) {
  int i = blockIdx.x * 256 + threadIdx.x;  // [0, B*E)
  int b = i >> 13;                         // E = 8192
  int h = heads[i], r = rels[i], t = tails[i];
  atomicAdd(&counts[(size_t)(b * N + h) * R + r], 1.0f);
  atomicAdd(&counts[(size_t)(b * N + t) * R + r], 1.0f);
}

// ---------------- out = relu(counts @ Wr), 4 rows/block, f32 acc -------------
__global__ __launch_bounds__(256) void out_kernel(const float* __restrict__ counts,
                                                  const float* __restrict__ Wr,
                                                  float* __restrict__ out) {
  int bn0 = blockIdx.x * TR;
  int o = threadIdx.x;
  __shared__ float crow[TR][R];
#pragma unroll
  for (int r = 0; r < TR; ++r) {
    crow[r][o] = counts[(size_t)(bn0 + r) * R + o];
    crow[r][o + 256] = counts[(size_t)(bn0 + r) * R + 256 + o];
  }
  __syncthreads();
  float acc[TR] = {0, 0, 0, 0};
  for (int k = 0; k < R; k += 4) {
    float w0 = Wr[(size_t)(k + 0) * O + o];
    float w1 = Wr[(size_t)(k + 1) * O + o];
    float w2 = Wr[(size_t)(k + 2) * O + o];
    float w3 = Wr[(size_t)(k + 3) * O + o];
#pragma unroll
    for (int r = 0; r < TR; ++r) {
      float4 cv = *(const float4*)&crow[r][k];
      acc[r] += cv.x * w0; acc[r] += cv.y * w1;
      acc[r] += cv.z * w2; acc[r] += cv.w * w3;
    }
  }
#pragma unroll
  for (int r = 0; r < TR; ++r)
    out[(size_t)(bn0 + r) * O + o] = fmaxf(acc[r], 0.0f);
}

extern "C" void kernel_launch(void* const* d_in, const int* in_sizes, int n_in,
                              void* d_out, int out_size, void* d_ws, size_t ws_size,
                              hipStream_t stream) {
  (void)in_sizes; (void)n_in; (void)out_size; (void)ws_size;
  const float* f2e   = (const float*)d_in[0];
  const float* score = (const float*)d_in[1];
  const float* relf  = (const float*)d_in[2];
  const float* Wk    = (const float*)d_in[3];
  const float* bk    = (const float*)d_in[4];
  // d_in[5] local_entity: unused by the reference computation
  const int* heads   = (const int*)d_in[6];
  const int* rels    = (const int*)d_in[7];
  const int* tails   = (const int*)d_in[8];
  const int* edge    = (const int*)d_in[9];
  const int* epsp    = (const int*)d_in[10];
  float* out = (float*)d_out;

  // workspace (floats): sim | logits | x2 | Wr | counts | cand | laux
  // scoreT/f2eT alias counts (dead before the post-cand memset).
  float* ws     = (float*)d_ws;
  float* sim    = ws;
  float* logits = sim + 524288;
  float* x2     = logits + 524288;
  float* Wr     = x2 + 2048;
  float* counts = Wr + 131072;                  // 4 MB
  float* scoreT = counts;                       // alias, 2 MB
  float* f2eT   = counts + 524288;              // alias, 2 MB
  unsigned char* cand = (unsigned char*)(counts + 1048576);
  float* laux   = (float*)(cand + 524288);

  transpose_kernel<<<256, 256, 0, stream>>>(score, scoreT, f2e, f2eT);
  x2_kernel<<<(B * N) / 256, 256, 0, stream>>>(f2e, x2);
  wr_kernel<<<R / TR, 256, 0, stream>>>(relf, Wk, bk, Wr);
  sim_kernel<<<(B * N) / TR, 256, 0, stream>>>(f2e, f2eT, x2, sim, logits, laux);
  cand_kernel<<<(B * N) / TR, 256, 0, stream>>>(sim, scoreT, edge, epsp, cand);
  hipMemsetAsync(counts, 0, (size_t)B * N * R * sizeof(float), stream);
  sample_kernel<<<(B * N * N) / 4, 256, 0, stream>>>(logits, laux, cand, edge, counts);
  batch_kernel<<<(B * E) / 256, 256, 0, stream>>>(heads, rels, tails, counts);
  out_kernel<<<(B * N) / TR, 256, 0, stream>>>(counts, Wr, out);
}